// Round 1
// baseline (264.183 us; speedup 1.0000x reference)
//
#include <hip/hip_runtime.h>
#include <hip/hip_bf16.h>

typedef __attribute__((ext_vector_type(8))) unsigned short ushort8;
typedef __attribute__((ext_vector_type(4))) float f32x4;
typedef __attribute__((ext_vector_type(8))) __bf16 bf16x8;

__device__ __forceinline__ float bf2f(unsigned short u) {
  union { unsigned u; float f; } v; v.u = ((unsigned)u) << 16; return v.f;
}
__device__ __forceinline__ unsigned short f2bf(float f) {
  union { float f; unsigned u; } v; v.f = f;
  unsigned r = v.u + 0x7FFFu + ((v.u >> 16) & 1u);
  return (unsigned short)(r >> 16);
}
__device__ __forceinline__ f32x4 mfma16(bf16x8 a, bf16x8 b, f32x4 c) {
  return __builtin_amdgcn_mfma_f32_16x16x32_bf16(a, b, c, 0, 0, 0);
}

// ---------------- weight transpose+cast: W[K][N] fp32 -> WT[row_off+n][k] bf16
__global__ __launch_bounds__(256) void transpose_cast(
    const float* __restrict__ W, unsigned short* __restrict__ WT,
    int K, int N, int ldwt, int row_off)
{
  __shared__ unsigned short t[64 * 80];
  int n0 = blockIdx.x * 64, k0 = blockIdx.y * 64;
  int tid = threadIdx.x;
#pragma unroll
  for (int i = 0; i < 4; i++) {
    int c = tid + 256 * i;          // 1024 float4 chunks: 64 rows x 16
    int r = c >> 4, q = c & 15;
    float4 v = *(const float4*)&W[(size_t)(k0 + r) * N + n0 + q * 4];
    t[(q * 4 + 0) * 80 + r] = f2bf(v.x);
    t[(q * 4 + 1) * 80 + r] = f2bf(v.y);
    t[(q * 4 + 2) * 80 + r] = f2bf(v.z);
    t[(q * 4 + 3) * 80 + r] = f2bf(v.w);
  }
  __syncthreads();
#pragma unroll
  for (int i = 0; i < 2; i++) {
    int c = tid + 256 * i;          // 512 ushort8 chunks: 64 n-rows x 8
    int n = c >> 3, p = c & 7;
    *(ushort8*)&WT[(size_t)(row_off + n0 + n) * ldwt + k0 + p * 8] =
        *(const ushort8*)&t[n * 80 + p * 8];
  }
}

__global__ void biascat_kernel(const float* __restrict__ bq, const float* __restrict__ bk,
                               const float* __restrict__ bv, const float* __restrict__ bg,
                               float* __restrict__ bcat)
{
  int i = blockIdx.x * 256 + threadIdx.x;   // 6144
  float v;
  if (i < 1024) v = bq[i];
  else if (i < 2048) v = bk[i - 1024];
  else if (i < 4096) v = bv[i - 2048];
  else v = bg[i - 4096];
  bcat[i] = v;
}

__global__ void cast_x_kernel(const float* __restrict__ x, unsigned short* __restrict__ xb)
{
  size_t i = (size_t)(blockIdx.x * 256 + threadIdx.x) * 4;
  float4 v = *(const float4*)&x[i];
  unsigned r0 = (unsigned)f2bf(v.x) | ((unsigned)f2bf(v.y) << 16);
  unsigned r1 = (unsigned)f2bf(v.z) | ((unsigned)f2bf(v.w) << 16);
  uint2 o; o.x = r0; o.y = r1;
  *(uint2*)&xb[i] = o;
}

// ---------------- GEMM: C[M][N] = A[M][K] @ BT[N][K]^T + bias, bf16 inputs
#define LDT 88
template<int OUT_BF16>
__global__ __launch_bounds__(256, 2) void gemm_kernel(
    const unsigned short* __restrict__ A, const unsigned short* __restrict__ BT,
    const float* __restrict__ bias, void* __restrict__ Cout,
    int M, int N, int K)
{
  __shared__ unsigned short As[128 * LDT];
  __shared__ unsigned short Bs[128 * LDT];
  int tid = threadIdx.x;
  int wave = tid >> 6, lane = tid & 63;
  int lr = lane & 15, lg = lane >> 4;
  int m0 = blockIdx.y * 128, n0 = blockIdx.x * 128;
  int wr = (wave >> 1) * 64, wc = (wave & 1) * 64;
  f32x4 acc[4][4] = {};
  for (int k0 = 0; k0 < K; k0 += 64) {
    __syncthreads();
#pragma unroll
    for (int i = 0; i < 4; i++) {
      int c = tid + 256 * i;        // 1024 chunks: 128 rows x 8
      int r = c >> 3, p = c & 7;
      *(ushort8*)&As[r * LDT + p * 8] = *(const ushort8*)&A[(size_t)(m0 + r) * K + k0 + p * 8];
      *(ushort8*)&Bs[r * LDT + p * 8] = *(const ushort8*)&BT[(size_t)(n0 + r) * K + k0 + p * 8];
    }
    __syncthreads();
#pragma unroll
    for (int kk = 0; kk < 2; kk++) {
      bf16x8 af[4], bfr[4];
#pragma unroll
      for (int m = 0; m < 4; m++)
        af[m] = *(const bf16x8*)&As[(wr + m * 16 + lr) * LDT + kk * 32 + lg * 8];
#pragma unroll
      for (int n = 0; n < 4; n++)
        bfr[n] = *(const bf16x8*)&Bs[(wc + n * 16 + lr) * LDT + kk * 32 + lg * 8];
#pragma unroll
      for (int m = 0; m < 4; m++)
#pragma unroll
        for (int n = 0; n < 4; n++)
          acc[m][n] = mfma16(af[m], bfr[n], acc[m][n]);
    }
  }
#pragma unroll
  for (int m = 0; m < 4; m++) {
#pragma unroll
    for (int n = 0; n < 4; n++) {
      int col = n0 + wc + n * 16 + lr;
      float bv = bias ? bias[col] : 0.f;
#pragma unroll
      for (int r = 0; r < 4; r++) {
        int row = m0 + wr + m * 16 + lg * 4 + r;
        float v = acc[m][n][r] + bv;
        if (OUT_BF16)
          ((unsigned short*)Cout)[(size_t)row * N + col] = f2bf(v);
        else
          ((float*)Cout)[(size_t)row * N + col] = v;
      }
    }
  }
}

// ---------------- prep: RoPE for q,k -> [BH][S][64] bf16
__global__ __launch_bounds__(256) void prep_qk_kernel(
    const unsigned short* __restrict__ Y,
    unsigned short* __restrict__ qr, unsigned short* __restrict__ kr)
{
  int t = blockIdx.x * 256 + threadIdx.x;  // [bs:4096][h:16][j:32]
  int j = t & 31;
  int h = (t >> 5) & 15;
  int bs = t >> 9;
  int s = bs & 2047;
  int b = bs >> 11;
  float ang = expf(-0.29710774f * (float)j);   // 10000^(-j/31)
  float th = (float)s * ang;
  float sn, cs;
  sincosf(th, &sn, &cs);
  const unsigned short* yq = &Y[(size_t)bs * 6144 + h * 64 + 2 * j];
  unsigned qv = *(const unsigned*)yq;
  unsigned kv = *(const unsigned*)(yq + 1024);
  float q0 = bf2f((unsigned short)(qv & 0xffff));
  float q1 = bf2f((unsigned short)(qv >> 16));
  float k0 = bf2f((unsigned short)(kv & 0xffff)) * 0.125f;
  float k1 = bf2f((unsigned short)(kv >> 16)) * 0.125f;
  float qr0 = q0 * cs - q1 * sn, qr1 = q1 * cs + q0 * sn;
  float kr0 = k0 * cs - k1 * sn, kr1 = k1 * cs + k0 * sn;
  size_t o = ((size_t)(b * 16 + h) * 2048 + s) * 64 + 2 * j;
  *(unsigned*)&qr[o] = (unsigned)f2bf(qr0) | ((unsigned)f2bf(qr1) << 16);
  *(unsigned*)&kr[o] = (unsigned)f2bf(kr0) | ((unsigned)f2bf(kr1) << 16);
}

// ---------------- prep: v transpose -> vT[BH][128][2048] bf16
__global__ __launch_bounds__(256) void prep_v_kernel(
    const unsigned short* __restrict__ Y, unsigned short* __restrict__ vT)
{
  __shared__ unsigned short t[128 * 80];
  int s0 = blockIdx.x * 64;
  int bh = blockIdx.y;
  int b = bh >> 4, h = bh & 15;
  int tid = threadIdx.x;
#pragma unroll
  for (int i = 0; i < 4; i++) {
    int c = tid + 256 * i;          // 1024: 64 rows x 16 chunks
    int r = c >> 4, p = c & 15;
    ushort8 v = *(const ushort8*)&Y[(size_t)(b * 2048 + s0 + r) * 6144 + 2048 + h * 128 + p * 8];
#pragma unroll
    for (int e = 0; e < 8; e++) t[(p * 8 + e) * 80 + r] = v[e];
  }
  __syncthreads();
#pragma unroll
  for (int i = 0; i < 4; i++) {
    int c = tid + 256 * i;          // 1024: 128 d x 8 chunks
    int d = c >> 3, p = c & 7;
    *(ushort8*)&vT[((size_t)bh * 128 + d) * 2048 + s0 + p * 8] = *(const ushort8*)&t[d * 80 + p * 8];
  }
}

// ---------------- prep: silu(g) -> gs[4096][2048] bf16
__global__ void prep_g_kernel(const unsigned short* __restrict__ Y, unsigned short* __restrict__ gs)
{
  int t = blockIdx.x * 256 + threadIdx.x;
  int bs = t >> 8, p = t & 255;
  ushort8 v = *(const ushort8*)&Y[(size_t)bs * 6144 + 4096 + p * 8];
  ushort8 o;
#pragma unroll
  for (int e = 0; e < 8; e++) {
    float g = bf2f((unsigned short)v[e]);
    o[e] = f2bf(g / (1.f + __expf(-g)));
  }
  *(ushort8*)&gs[(size_t)bs * 2048 + p * 8] = o;
}

// ---------------- retention: per (bh, 64 q-rows) flash-style causal decay
__global__ __launch_bounds__(256, 2) void retention_kernel(
    const unsigned short* __restrict__ qr, const unsigned short* __restrict__ kr,
    const unsigned short* __restrict__ vT, const unsigned short* __restrict__ gs,
    unsigned short* __restrict__ Z)
{
  __shared__ unsigned short lk[64 * 88];
  __shared__ unsigned short lv[128 * 88];
  __shared__ unsigned short lp[4 * 16 * 88];
  int s0 = (31 - blockIdx.x) * 64;     // heavy tiles first
  int bh = blockIdx.y;
  int b = bh >> 4, h = bh & 15;
  float decay = logf(1.f - exp2f(-5.f - (float)h));
  int tid = threadIdx.x, wave = tid >> 6, lane = tid & 63;
  int lr = lane & 15, lg = lane >> 4;
  const unsigned short* qbase = &qr[(size_t)bh * 2048 * 64];
  const unsigned short* kbase = &kr[(size_t)bh * 2048 * 64];
  const unsigned short* vbase = &vT[(size_t)bh * 128 * 2048];

  int qrow = s0 + wave * 16 + lr;
  bf16x8 qf0 = *(const bf16x8*)&qbase[(size_t)qrow * 64 + lg * 8];
  bf16x8 qf1 = *(const bf16x8*)&qbase[(size_t)qrow * 64 + 32 + lg * 8];

  f32x4 accv[8] = {};
  float rs[4] = {0.f, 0.f, 0.f, 0.f};
  unsigned short* lpw = &lp[wave * 16 * 88];

  for (int t0 = 0; t0 <= s0; t0 += 64) {
    __syncthreads();
#pragma unroll
    for (int i = 0; i < 2; i++) {
      int c = tid + 256 * i;         // 512: 64 rows x 8
      int r = c >> 3, p = c & 7;
      *(ushort8*)&lk[r * 88 + p * 8] = *(const ushort8*)&kbase[(size_t)(t0 + r) * 64 + p * 8];
    }
#pragma unroll
    for (int i = 0; i < 4; i++) {
      int c = tid + 256 * i;         // 1024: 128 d x 8
      int d = c >> 3, p = c & 7;
      *(ushort8*)&lv[d * 88 + p * 8] = *(const ushort8*)&vbase[(size_t)d * 2048 + t0 + p * 8];
    }
    __syncthreads();
    // S-tile: 16 q-rows x 64 keys per wave, weight + rowsum + P->LDS(bf16)
#pragma unroll
    for (int nb = 0; nb < 4; nb++) {
      f32x4 sa = {};
      {
        bf16x8 b0 = *(const bf16x8*)&lk[(nb * 16 + lr) * 88 + lg * 8];
        sa = mfma16(qf0, b0, sa);
        bf16x8 b1 = *(const bf16x8*)&lk[(nb * 16 + lr) * 88 + 32 + lg * 8];
        sa = mfma16(qf1, b1, sa);
      }
      int tc = t0 + nb * 16 + lr;
#pragma unroll
      for (int r = 0; r < 4; r++) {
        int sr = s0 + wave * 16 + lg * 4 + r;
        int dlt = sr - tc;
        float w = (dlt >= 0) ? __expf(decay * (float)dlt) : 0.f;
        float val = sa[r] * w;
        rs[r] += val;
        lpw[(lg * 4 + r) * 88 + nb * 16 + lr] = f2bf(val);
      }
    }
    // PV: out[16][128] += P[16][64] @ V[64][128]
#pragma unroll
    for (int kk = 0; kk < 2; kk++) {
      bf16x8 pa = *(const bf16x8*)&lpw[lr * 88 + kk * 32 + lg * 8];
#pragma unroll
      for (int nb = 0; nb < 8; nb++) {
        bf16x8 bv = *(const bf16x8*)&lv[(nb * 16 + lr) * 88 + kk * 32 + lg * 8];
        accv[nb] = mfma16(pa, bv, accv[nb]);
      }
    }
  }
  // epilogue: rowsum reduce, geo-norm, denom, LayerNorm, gate
#pragma unroll
  for (int r = 0; r < 4; r++) {
    float v = rs[r];
    v += __shfl_xor(v, 1); v += __shfl_xor(v, 2);
    v += __shfl_xor(v, 4); v += __shfl_xor(v, 8);
    rs[r] = v;
  }
  int srb = s0 + wave * 16 + lg * 4;
  float scl[4], mean[4], istd[4];
#pragma unroll
  for (int r = 0; r < 4; r++) {
    float sidx = (float)(srb + r);
    float geo = (1.f - __expf(decay * (sidx + 1.f))) * exp2f(5.f + (float)h);
    float invs = rsqrtf(geo);
    float den = fmaxf(fabsf(rs[r] * invs), 1.f);
    scl[r] = invs / den;
    float sm = 0.f, sq = 0.f;
#pragma unroll
    for (int nb = 0; nb < 8; nb++) {
      float v = accv[nb][r] * scl[r];
      sm += v; sq += v * v;
    }
    sm += __shfl_xor(sm, 1); sm += __shfl_xor(sm, 2);
    sm += __shfl_xor(sm, 4); sm += __shfl_xor(sm, 8);
    sq += __shfl_xor(sq, 1); sq += __shfl_xor(sq, 2);
    sq += __shfl_xor(sq, 4); sq += __shfl_xor(sq, 8);
    float mu = sm * (1.f / 128.f);
    float var = sq * (1.f / 128.f) - mu * mu;
    mean[r] = mu;
    istd[r] = rsqrtf(var + 1e-5f);
  }
  const unsigned short* gsb = &gs[((size_t)b * 2048 + srb) * 2048 + h * 128];
  unsigned short* zb = &Z[((size_t)b * 2048 + srb) * 2048 + h * 128];
#pragma unroll
  for (int nb = 0; nb < 8; nb++) {
#pragma unroll
    for (int r = 0; r < 4; r++) {
      float v = accv[nb][r] * scl[r];
      float nrm = (v - mean[r]) * istd[r];
      float g = bf2f(gsb[(size_t)r * 2048 + nb * 16 + lr]);
      zb[(size_t)r * 2048 + nb * 16 + lr] = f2bf(nrm * g);
    }
  }
}

extern "C" void kernel_launch(void* const* d_in, const int* in_sizes, int n_in,
                              void* d_out, int out_size, void* d_ws, size_t ws_size,
                              hipStream_t stream) {
  const float* x  = (const float*)d_in[0];
  const float* Wq = (const float*)d_in[1];
  const float* bq = (const float*)d_in[2];
  const float* Wk = (const float*)d_in[3];
  const float* bk = (const float*)d_in[4];
  const float* Wv = (const float*)d_in[5];
  const float* bv = (const float*)d_in[6];
  const float* Wg = (const float*)d_in[7];
  const float* bg = (const float*)d_in[8];
  const float* Wo = (const float*)d_in[9];
  const float* bo = (const float*)d_in[10];

  char* ws = (char*)d_ws;
  unsigned short* wcatT = (unsigned short*)(ws);                 // [6144][1024]   12.6 MB
  unsigned short* woT   = (unsigned short*)(ws + 12582912);      // [1024][2048]    4.2 MB
  unsigned short* xbf   = (unsigned short*)(ws + 16777216);      // [4096][1024]    8.4 MB
  unsigned short* Y     = (unsigned short*)(ws + 25165824);      // [4096][6144]   50.3 MB
  unsigned short* qrb   = (unsigned short*)(ws + 75497472);      // [32][2048][64]  8.4 MB
  unsigned short* krb   = (unsigned short*)(ws + 83886080);      // [32][2048][64]  8.4 MB
  unsigned short* vT    = (unsigned short*)(ws + 92274688);      // [32][128][2048] 16.8 MB
  unsigned short* gs    = (unsigned short*)(ws + 109051904);     // [4096][2048]   16.8 MB
  float*          bcat  = (float*)(ws + 125829120);              // [6144]
  unsigned short* Z     = Y;  // Y is dead after prep kernels; reuse for gated output

  // weights -> transposed bf16
  transpose_cast<<<dim3(16, 16), 256, 0, stream>>>(Wq, wcatT, 1024, 1024, 1024, 0);
  transpose_cast<<<dim3(16, 16), 256, 0, stream>>>(Wk, wcatT, 1024, 1024, 1024, 1024);
  transpose_cast<<<dim3(32, 16), 256, 0, stream>>>(Wv, wcatT, 1024, 2048, 1024, 2048);
  transpose_cast<<<dim3(32, 16), 256, 0, stream>>>(Wg, wcatT, 1024, 2048, 1024, 4096);
  transpose_cast<<<dim3(16, 32), 256, 0, stream>>>(Wo, woT, 2048, 1024, 2048, 0);
  biascat_kernel<<<24, 256, 0, stream>>>(bq, bk, bv, bg, bcat);
  cast_x_kernel<<<4096, 256, 0, stream>>>(x, xbf);

  // fused QKVG projection: Y = x @ [Wq|Wk|Wv|Wg] + bias (bf16 out)
  gemm_kernel<1><<<dim3(48, 32), 256, 0, stream>>>(xbf, wcatT, bcat, Y, 4096, 6144, 1024);

  // prep: RoPE(q,k), v-transpose, silu(g)
  prep_qk_kernel<<<8192, 256, 0, stream>>>(Y, qrb, krb);
  prep_v_kernel<<<dim3(32, 32), 256, 0, stream>>>(Y, vT);
  prep_g_kernel<<<4096, 256, 0, stream>>>(Y, gs);

  // retention + LN + gate -> Z (bf16)
  retention_kernel<<<dim3(32, 32), 256, 0, stream>>>(qrb, krb, vT, gs, Z);

  // output projection: out = Z @ Wo + bo (fp32 out)
  gemm_kernel<0><<<dim3(8, 32), 256, 0, stream>>>(Z, woT, bo, d_out, 4096, 1024, 2048);
}